// Round 4
// baseline (145.506 us; speedup 1.0000x reference)
//
#include <hip/hip_runtime.h>
#include <hip/hip_bf16.h>
#include <hip/hip_fp16.h>
#include <math.h>

#define NB 16
#define NC 16
#define NP 2048
#define NK 16
#define NE 64
#define NH 2
#define EPSV 1e-5f
#define NSLOPE 0.2f
#define QINV -1e30f
#define QTHR -1e29f

// workspace byte offsets (ws poisoned 0xAA each iter; everything rewritten each call)
#define WS_PINFO 16384                         // float4[B*P] = 2 MiB
#define WS_ENT   540672                        // uint2[B*P*16] = 4 MiB (16-aligned)
#define WS_CNT   4734976                       // u8[B*P] = 32 KiB

__device__ __forceinline__ float ldf(const void* p, int i, int isb) {
  return isb ? __bfloat162float(((const __hip_bfloat16*)p)[i]) : ((const float*)p)[i];
}
__device__ __forceinline__ unsigned f2bf(float f) {          // RNE f32->bf16 bits
  unsigned u = __float_as_uint(f);
  return (u + 0x7FFFu + ((u >> 16) & 1u)) >> 16;
}
__device__ __forceinline__ float bflo(unsigned v) { return __uint_as_float(v << 16); }
__device__ __forceinline__ float bfhi(unsigned v) { return __uint_as_float(v & 0xFFFF0000u); }

// ---------------- kernel 0: pinfo {q0m, q1m, ss0, ss1} ----------------------
// grid 128 = b(16) x chunk(8 of 256 p)
__global__ void __launch_bounds__(256) k_pinfo(
    const void* feat, const void* mask,
    const void* edge_w, const void* node_w,
    const void* edge_g, const void* edge_v,
    const void* node_g, const void* node_v, const void* node_b, const void* node_m,
    const void* self_w, const void* self_b, const void* nb_w,
    char* ws)
{
  __shared__ int sh_isb, sh_mbyte;
  __shared__ float ewl[128*17], nwl[128*17];
  __shared__ float w2[128], wn[128], ctr[128];
  __shared__ float s_wq[32], s_wsc[32], s_cself[2];

  const int tid = threadIdx.x;
  const int w = tid >> 6, lane = tid & 63;

  if (w == 0) {      // bf16 N(0,1): exponent field in [100,135] for ~all samples
    const unsigned short* u = (const unsigned short*)feat;
    int cnt = 0;
#pragma unroll
    for (int i = 0; i < 8; i++) {
      int ex = (u[lane*8 + i] >> 7) & 0xFF;
      cnt += (ex >= 100 && ex <= 135) ? 1 : 0;
    }
#pragma unroll
    for (int o = 32; o >= 1; o >>= 1) cnt += __shfl_xor(cnt, o);
    if (lane == 0) sh_isb = (cnt >= 460) ? 1 : 0;
  }
  if (w == 1) {      // int32 0/1 mask has all non-aligned bytes zero
    const unsigned char* mb = (const unsigned char*)mask;
    int c = 0;
#pragma unroll
    for (int i = 0; i < 16; i++) {
      int ix = lane*16 + i;
      c += ((ix & 3) && mb[ix]) ? 1 : 0;
    }
#pragma unroll
    for (int o = 32; o >= 1; o >>= 1) c += __shfl_xor(c, o);
    if (lane == 0) sh_mbyte = (c > 0) ? 1 : 0;
  }
  __syncthreads();
  const int isb = sh_isb, mbyte = sh_mbyte;

  for (int i = tid; i < 128*16; i += 256) {
    const int he = i >> 4, c = i & 15;
    ewl[he*17 + c] = ldf(edge_w, i, isb);
    nwl[he*17 + c] = ldf(node_w, i, isb);
  }
  if (tid < 128) {
    const int he = tid;
    float se = ldf(edge_g, he, isb) * rsqrtf(ldf(edge_v, he, isb) + EPSV);
    float ns = ldf(node_g, he, isb) * rsqrtf(ldf(node_v, he, isb) + EPSV);
    w2[he]  = ldf(nb_w, he, isb) * se;
    wn[he]  = ldf(self_w, he, isb) * ns;
    ctr[he] = ldf(self_w, he, isb) * (ldf(node_b, he, isb) - ldf(node_m, he, isb) * ns);
  }
  __syncthreads();
  if (tid < 32) {
    const int h = tid >> 4, c = tid & 15;
    float sq = 0.f, sn = 0.f;
#pragma unroll 8
    for (int e = 0; e < NE; e++) {
      sq += w2[h*NE+e] * ewl[(h*NE+e)*17 + c];
      sn += wn[h*NE+e] * nwl[(h*NE+e)*17 + c];
    }
    s_wq[tid]  = sq;
    s_wsc[tid] = sn;
  }
  if (tid < 2) {
    float cs = 0.f;
#pragma unroll 8
    for (int e = 0; e < NE; e++) cs += ctr[tid*NE+e];
    s_cself[tid] = cs + ldf(self_b, tid, isb);
  }
  __syncthreads();

  const int bid = blockIdx.x;
  const int b = (bid & 7)*2 + ((bid >> 3) & 1);     // XCD swizzle
  const int chunk = bid >> 4;
  const int p = chunk*256 + w*64 + lane;

  float q0=0.f, q1=0.f, s0=0.f, s1=0.f;
#pragma unroll
  for (int c = 0; c < NC; c++) {
    const float fc = ldf(feat, (b*NC + c)*NP + p, isb);
    q0 = fmaf(s_wq[c],     fc, q0);
    q1 = fmaf(s_wq[16+c],  fc, q1);
    s0 = fmaf(s_wsc[c],    fc, s0);
    s1 = fmaf(s_wsc[16+c], fc, s1);
  }
  bool mv;
  if (mbyte) mv = ((const unsigned char*)mask)[b*NP + p] != 0;
  else       mv = ((const int*)mask)[b*NP + p] != 0;
  float4 pi;
  pi.x = mv ? q0 : QINV;
  pi.y = mv ? q1 : QINV;
  pi.z = s0 + s_cself[0];
  pi.w = s1 + s_cself[1];
  ((float4*)(ws + WS_PINFO))[b*NP + p] = pi;
}

// ---------------- kernel 1: softmax coef, compacted entries -----------------
// grid 128 = b(16) x chunk(8 of 256 p); 4 waves x 16 passes x 4 p
__global__ void __launch_bounds__(256) k_coef(
    const void* feat, const int* nidx,
    const void* edge_g, const void* edge_v, const void* edge_bias,
    const void* edge_m, const void* edge_b2,
    const void* nb_w, const void* nb_b,
    char* ws)
{
  __shared__ int sh_isb;
  __shared__ float sh_cnb[2];
  const int tid = threadIdx.x;
  const int w = tid >> 6, lane = tid & 63;

  if (w == 0) {
    const unsigned short* u = (const unsigned short*)feat;
    int cnt = 0;
#pragma unroll
    for (int i = 0; i < 8; i++) {
      int ex = (u[lane*8 + i] >> 7) & 0xFF;
      cnt += (ex >= 100 && ex <= 135) ? 1 : 0;
    }
#pragma unroll
    for (int o = 32; o >= 1; o >>= 1) cnt += __shfl_xor(cnt, o);
    if (lane == 0) sh_isb = (cnt >= 460) ? 1 : 0;
  }
  __syncthreads();
  const int isb = sh_isb;

  if (tid < 128) {
    const int he = tid, h = tid >> 6;
    float se = ldf(edge_g, he, isb) * rsqrtf(ldf(edge_v, he, isb) + EPSV);
    float cb = se * (ldf(edge_bias, he, isb) - ldf(edge_m, he, isb)) + ldf(edge_b2, he, isb);
    float t = ldf(nb_w, he, isb) * cb;
#pragma unroll
    for (int o = 32; o >= 1; o >>= 1) t += __shfl_xor(t, o);
    if ((tid & 63) == 0) sh_cnb[h] = t + ldf(nb_b, h, isb);
  }
  __syncthreads();

  const float4* pinfo = (const float4*)(ws + WS_PINFO);
  uint2* ent = (uint2*)(ws + WS_ENT);
  unsigned char* cntg = (unsigned char*)(ws + WS_CNT);

  const int bid = blockIdx.x;
  const int b = (bid & 7)*2 + ((bid >> 3) & 1);
  const int chunk = bid >> 4;
  const int jj = lane >> 4, kk = lane & 15;
  const float cnb0 = sh_cnb[0], cnb1 = sh_cnb[1];

  for (int s = 0; s < 16; s++) {
    const int p4 = chunk*256 + w*64 + s*4;
    const int idx_l = nidx[(b*NP + p4)*NK + lane];   // 256B coalesced
    const float4 P  = pinfo[b*NP + idx_l];
    const float4 Pc = pinfo[b*NP + p4 + jj];
    const bool valid = (P.x > QTHR);
    const unsigned long long vm = __ballot(valid);
    const unsigned vmj = (unsigned)((vm >> (16*jj)) & 0xFFFFull);
    const bool anyv = (vmj != 0);

    float c0, c1;
    {
      float l0 = Pc.z + P.x - Pc.x + cnb0;
      l0 = (l0 >= 0.f) ? l0 : NSLOPE * l0;
      float mx = l0;
#pragma unroll
      for (int o = 8; o >= 1; o >>= 1) mx = fmaxf(mx, __shfl_xor(mx, o));
      float ex = __expf(l0 - mx);
      float sm = ex;
#pragma unroll
      for (int o = 8; o >= 1; o >>= 1) sm += __shfl_xor(sm, o);
      c0 = anyv ? ex / sm : 0.f;
    }
    {
      float l1 = Pc.w + P.y - Pc.y + cnb1;
      l1 = (l1 >= 0.f) ? l1 : NSLOPE * l1;
      float mx = l1;
#pragma unroll
      for (int o = 8; o >= 1; o >>= 1) mx = fmaxf(mx, __shfl_xor(mx, o));
      float ex = __expf(l1 - mx);
      float sm = ex;
#pragma unroll
      for (int o = 8; o >= 1; o >>= 1) sm += __shfl_xor(sm, o);
      c1 = anyv ? ex / sm : 0.f;
    }
    const int pos = __popc(vmj & ((1u << kk) - 1));
    if (valid) {
      __half2 h2 = __floats2half2_rn(c0, c1);
      uint2 e;
      e.x = *(unsigned*)&h2;
      e.y = (unsigned)idx_l;
      ent[(long)(b*NP + p4 + jj)*NK + pos] = e;
    }
    if (kk == 0) {
      const int cm = (Pc.x > QTHR) ? 0x80 : 0;
      cntg[b*NP + p4 + jj] = (unsigned char)(__popc(vmj) | cm);
    }
  }
}

// ---------------- kernel 2: eproj tile in LDS + gather + outputs ------------
// grid 512 = b(16) x ec(16 chunks of 4 e) x ph(2 halves of 1024 p)
__global__ void __launch_bounds__(256) k_gather(
    const void* feat, const void* edge_w,
    const void* edge_g, const void* edge_v, const void* edge_bias,
    const void* edge_m, const void* edge_b2,
    char* ws, void* out)
{
  __shared__ int sh_isb;
  __shared__ unsigned epl[NP*4];          // [p][e] bf16x2(h0,h1), 32 KiB
  __shared__ uint2 entw[4][32][17];       // per-wave staged entries, 17.4 KiB
  __shared__ float wzl[8*16];             // eproj weights for own 8 (e,h)
  __shared__ float secb[16];              // se[0..7]=(e*2+h), cb[8..15]

  const int tid = threadIdx.x;
  const int w = tid >> 6, lane = tid & 63;

  if (w == 0) {
    const unsigned short* u = (const unsigned short*)feat;
    int cnt = 0;
#pragma unroll
    for (int i = 0; i < 8; i++) {
      int ex = (u[lane*8 + i] >> 7) & 0xFF;
      cnt += (ex >= 100 && ex <= 135) ? 1 : 0;
    }
#pragma unroll
    for (int o = 32; o >= 1; o >>= 1) cnt += __shfl_xor(cnt, o);
    if (lane == 0) sh_isb = (cnt >= 460) ? 1 : 0;
  }
  __syncthreads();
  const int isb = sh_isb;

  const int bid = blockIdx.x;
  const int b  = (bid & 7)*2 + ((bid >> 3) & 1);    // XCD swizzle
  const int r  = bid >> 4;
  const int ec = r & 15;
  const int ph = r >> 4;

  if (tid < 128) {                       // wz[u][c], u=(e*2+h)
    const int u = tid >> 4, c = tid & 15;
    const int e = u >> 1, h = u & 1;
    wzl[u*16 + c] = ldf(edge_w, (h*NE + ec*4 + e)*NC + c, isb);
  }
  if (tid < 8) {
    const int e = tid >> 1, h = tid & 1;
    const int he = h*NE + ec*4 + e;
    float se = ldf(edge_g, he, isb) * rsqrtf(ldf(edge_v, he, isb) + EPSV);
    float cb = se * (ldf(edge_bias, he, isb) - ldf(edge_m, he, isb)) + ldf(edge_b2, he, isb);
    secb[tid]     = se;
    secb[8 + tid] = cb;
  }
  __syncthreads();

  // ---- phase 1: full 2048-p eproj tile for own 4 e's, bf16x2-packed ----
  for (int t = w; t < 32; t += 4) {
    const int p = t*64 + lane;
    float acc[8] = {0.f,0.f,0.f,0.f,0.f,0.f,0.f,0.f};
#pragma unroll
    for (int c = 0; c < NC; c++) {
      const float fc = ldf(feat, (b*NC + c)*NP + p, isb);
#pragma unroll
      for (int u = 0; u < 8; u++) acc[u] = fmaf(wzl[u*16 + c], fc, acc[u]);
    }
    uint4 pk;
    pk.x = f2bf(acc[0]) | (f2bf(acc[1]) << 16);
    pk.y = f2bf(acc[2]) | (f2bf(acc[3]) << 16);
    pk.z = f2bf(acc[4]) | (f2bf(acc[5]) << 16);
    pk.w = f2bf(acc[6]) | (f2bf(acc[7]) << 16);
    *(uint4*)&epl[p*4] = pk;             // classic stride-1 b128 write
  }
  __syncthreads();

  // ---- phase 2: LDS gather; lanes = (u = e-pair, pi = p in group of 32) ----
  const int u = lane >> 5, pi = lane & 31;
  const float sea0 = secb[u*4 + 0], sea1 = secb[u*4 + 1];   // e_a=(u*2): h0,h1
  const float seb0 = secb[u*4 + 2], seb1 = secb[u*4 + 3];   // e_b=(u*2+1)
  const float cba0 = secb[8 + u*4 + 0], cba1 = secb[8 + u*4 + 1];
  const float cbb0 = secb[8 + u*4 + 2], cbb1 = secb[8 + u*4 + 3];

  const uint4* entg = (const uint4*)(ws + WS_ENT);
  const unsigned char* cntg = (const unsigned char*)(ws + WS_CNT);
  const long go = (long)NB * NE * NP;

  for (int g = 0; g < 8; g++) {
    const int pg = ph*1024 + w*256 + g*32;
    // stage 32p x 16k entries (4 KiB) into per-wave LDS
    const long eb4 = (long)(b*NP + pg) * 8;           // uint4 units
#pragma unroll
    for (int ps = 0; ps < 4; ps++) {
      const int li4 = ps*64 + lane;
      const uint4 v = entg[eb4 + li4];
      const int pl = li4 >> 3, k0 = (li4 & 7) * 2;
      entw[w][pl][k0]     = make_uint2(v.x, v.y);
      entw[w][pl][k0 + 1] = make_uint2(v.z, v.w);
    }
    const unsigned cc = cntg[b*NP + pg + pi];
    const int cnte = (cc & 0x80) ? (int)(cc & 0x7F) : 0;

    const uint2 ce = *(const uint2*)&epl[(pg + pi)*4 + u*2];
    const float ra0 = bflo(ce.x), ra1 = bfhi(ce.x);
    const float rb0 = bflo(ce.y), rb1 = bfhi(ce.y);
    const float cpa0 = cba0 - sea0*ra0, cpa1 = cba1 - sea1*ra1;
    const float cpb0 = cbb0 - seb0*rb0, cpb1 = cbb1 - seb1*rb1;

    float aa0=0.f, aa1=0.f, ab0=0.f, ab1=0.f;
    float mxa0=-INFINITY, mna0=INFINITY, mxa1=-INFINITY, mna1=INFINITY;
    float mxb0=-INFINITY, mnb0=INFINITY, mxb1=-INFINITY, mnb1=INFINITY;
    for (int k = 0; k < cnte; k++) {
      const uint2 en = entw[w][pi][k];
      const __half2 hc = *(const __half2*)&en.x;
      const float c0 = __low2float(hc), c1 = __high2float(hc);
      const uint2 pv = *(const uint2*)&epl[en.y*4 + u*2];
      const float va0 = bflo(pv.x), va1 = bfhi(pv.x);
      const float vb0 = bflo(pv.y), vb1 = bfhi(pv.y);
      aa0 = fmaf(c0, va0, aa0); aa1 = fmaf(c1, va1, aa1);
      ab0 = fmaf(c0, vb0, ab0); ab1 = fmaf(c1, vb1, ab1);
      mxa0 = fmaxf(mxa0, va0); mna0 = fminf(mna0, va0);
      mxa1 = fmaxf(mxa1, va1); mna1 = fminf(mna1, va1);
      mxb0 = fmaxf(mxb0, vb0); mnb0 = fminf(mnb0, vb0);
      mxb1 = fmaxf(mxb1, vb1); mnb1 = fminf(mnb1, vb1);
    }
    const bool av = (cnte > 0);
    const float csel = av ? 1.f : 0.f;
    const float ta0 = fmaxf(fmaf(sea0, aa0, cpa0*csel), 0.f);
    const float ta1 = fmaxf(fmaf(sea1, aa1, cpa1*csel), 0.f);
    const float tb0 = fmaxf(fmaf(seb0, ab0, cpb0*csel), 0.f);
    const float tb1 = fmaxf(fmaf(seb1, ab1, cpb1*csel), 0.f);
    const float atta = fmaxf(ta0, ta1);
    const float attb = fmaxf(tb0, tb1);
    const float ga0 = av ? fmaf(sea0, (sea0 >= 0.f) ? mxa0 : mna0, cpa0) : 0.f;
    const float ga1 = av ? fmaf(sea1, (sea1 >= 0.f) ? mxa1 : mna1, cpa1) : 0.f;
    const float gb0 = av ? fmaf(seb0, (seb0 >= 0.f) ? mxb0 : mnb0, cpb0) : 0.f;
    const float gb1 = av ? fmaf(seb1, (seb1 >= 0.f) ? mxb1 : mnb1, cpb1) : 0.f;
    const float gra = fmaxf(ga0, ga1);
    const float grb = fmaxf(gb0, gb1);

    const long oa = (long)(b*NE + ec*4 + u*2) * NP + pg + pi;
    const long ob = oa + NP;             // next e row
    if (isb) {
      __hip_bfloat16* o = (__hip_bfloat16*)out;
      o[oa] = __float2bfloat16(atta);  o[ob] = __float2bfloat16(attb);
      o[oa + go] = __float2bfloat16(gra); o[ob + go] = __float2bfloat16(grb);
    } else {
      float* o = (float*)out;
      o[oa] = atta;  o[ob] = attb;
      o[oa + go] = gra; o[ob + go] = grb;
    }
  }
}

extern "C" void kernel_launch(void* const* d_in, const int* in_sizes, int n_in,
                              void* d_out, int out_size, void* d_ws, size_t ws_size,
                              hipStream_t stream)
{
  const void* feat      = d_in[0];
  const void* nidx      = d_in[1];
  const void* mask      = d_in[2];
  const void* node_w    = d_in[3];
  const void* node_g    = d_in[4];
  const void* node_b    = d_in[5];
  const void* node_m    = d_in[6];
  const void* node_v    = d_in[7];
  const void* edge_w    = d_in[8];
  const void* edge_bias = d_in[9];
  const void* edge_g    = d_in[10];
  const void* edge_b2   = d_in[11];
  const void* edge_m    = d_in[12];
  const void* edge_v    = d_in[13];
  const void* self_w    = d_in[14];
  const void* self_b    = d_in[15];
  const void* nb_w      = d_in[16];
  const void* nb_b      = d_in[17];
  char* ws = (char*)d_ws;

  hipLaunchKernelGGL(k_pinfo, dim3(128), dim3(256), 0, stream,
                     feat, mask, edge_w, node_w,
                     edge_g, edge_v,
                     node_g, node_v, node_b, node_m,
                     self_w, self_b, nb_w, ws);
  hipLaunchKernelGGL(k_coef, dim3(128), dim3(256), 0, stream,
                     feat, (const int*)nidx,
                     edge_g, edge_v, edge_bias, edge_m, edge_b2,
                     nb_w, nb_b, ws);
  hipLaunchKernelGGL(k_gather, dim3(512), dim3(256), 0, stream,
                     feat, edge_w,
                     edge_g, edge_v, edge_bias, edge_m, edge_b2,
                     ws, d_out);
}

// Round 5
// 122.735 us; speedup vs baseline: 1.1855x; 1.1855x over previous
//
#include <hip/hip_runtime.h>
#include <hip/hip_bf16.h>
#include <hip/hip_fp16.h>
#include <math.h>

#define NB 16
#define NC 16
#define NP 2048
#define NK 16
#define NE 64
#define NH 2
#define EPSV 1e-5f
#define NSLOPE 0.2f
#define QINV -1e30f
#define QTHR -1e29f

// workspace byte offsets (ws poisoned 0xAA each iter; fully rewritten each call)
#define WS_PINFO 16384                 // float4[B*P] = 2 MiB
#define WS_EPB   2162688               // uint[B*P*64] bf16x2(h0,h1) = 8 MiB

__device__ __forceinline__ float ldf(const void* p, int i, int isb) {
  return isb ? __bfloat162float(((const __hip_bfloat16*)p)[i]) : ((const float*)p)[i];
}
__device__ __forceinline__ unsigned f2bf(float f) {          // RNE f32->bf16 bits
  unsigned u = __float_as_uint(f);
  return (u + 0x7FFFu + ((u >> 16) & 1u)) >> 16;
}
__device__ __forceinline__ float bflo(unsigned v) { return __uint_as_float(v << 16); }
__device__ __forceinline__ float bfhi(unsigned v) { return __uint_as_float(v & 0xFFFF0000u); }

// ---------------- kernel 1: projection (bf16x2-packed) + pinfo --------------
// grid: NB*(NP/64) = 512 blocks; XCD swizzle matches k_main
__global__ void __launch_bounds__(256) k_proj(
    const void* feat, const void* mask,
    const void* edge_w, const void* node_w,
    const void* edge_g, const void* edge_v,
    const void* node_g, const void* node_v, const void* node_b, const void* node_m,
    const void* self_w, const void* self_b, const void* nb_w,
    char* ws)
{
  __shared__ int sh_isb, sh_mbyte;
  __shared__ float ewl[128*17];        // padded [he][c]
  __shared__ float nwl[128*17];
  __shared__ float fl[NC][64];
  __shared__ float w2[128], wn[128], ctr[128];
  __shared__ float s_wq[32], s_wsc[32], s_cself[2];

  const int tid = threadIdx.x;
  const int w = tid >> 6, lane = tid & 63;

  if (w == 0) {      // bf16 N(0,1): exponent field in [100,135] for ~all samples
    const unsigned short* u = (const unsigned short*)feat;
    int cnt = 0;
#pragma unroll
    for (int i = 0; i < 8; i++) {
      int ex = (u[lane*8 + i] >> 7) & 0xFF;
      cnt += (ex >= 100 && ex <= 135) ? 1 : 0;
    }
#pragma unroll
    for (int o = 32; o >= 1; o >>= 1) cnt += __shfl_xor(cnt, o);
    if (lane == 0) sh_isb = (cnt >= 460) ? 1 : 0;
  }
  if (w == 1) {      // int32 0/1 mask has all non-aligned bytes zero
    const unsigned char* mb = (const unsigned char*)mask;
    int c = 0;
#pragma unroll
    for (int i = 0; i < 16; i++) {
      int ix = lane*16 + i;
      c += ((ix & 3) && mb[ix]) ? 1 : 0;
    }
#pragma unroll
    for (int o = 32; o >= 1; o >>= 1) c += __shfl_xor(c, o);
    if (lane == 0) sh_mbyte = (c > 0) ? 1 : 0;
  }
  __syncthreads();
  const int isb = sh_isb, mbyte = sh_mbyte;

  const int bid = blockIdx.x;
  const int b  = (bid & 7)*2 + ((bid >> 3) & 1);   // XCD swizzle
  const int pt = bid >> 4;                         // 0..31
  const int p0 = pt * 64;

  for (int i = tid; i < 128*16; i += 256) {
    const int he = i >> 4, c = i & 15;
    ewl[he*17 + c] = ldf(edge_w, i, isb);
    nwl[he*17 + c] = ldf(node_w, i, isb);
  }
  for (int i = tid; i < NC*64; i += 256) {
    int c = i >> 6, p = i & 63;
    fl[c][p] = ldf(feat, (b*NC + c)*NP + p0 + p, isb);
  }
  if (tid < 128) {
    const int he = tid;
    float se = ldf(edge_g, he, isb) * rsqrtf(ldf(edge_v, he, isb) + EPSV);
    float ns = ldf(node_g, he, isb) * rsqrtf(ldf(node_v, he, isb) + EPSV);
    w2[he]  = ldf(nb_w, he, isb) * se;
    wn[he]  = ldf(self_w, he, isb) * ns;
    ctr[he] = ldf(self_w, he, isb) * (ldf(node_b, he, isb) - ldf(node_m, he, isb) * ns);
  }
  __syncthreads();
  if (tid < 32) {
    const int h = tid >> 4, c = tid & 15;
    float sq = 0.f, sn = 0.f;
#pragma unroll 8
    for (int e = 0; e < NE; e++) {
      sq += w2[h*NE+e] * ewl[(h*NE+e)*17 + c];
      sn += wn[h*NE+e] * nwl[(h*NE+e)*17 + c];
    }
    s_wq[tid]  = sq;
    s_wsc[tid] = sn;
  }
  if (tid < 2) {
    float cs = 0.f;
#pragma unroll 8
    for (int e = 0; e < NE; e++) cs += ctr[tid*NE+e];
    s_cself[tid] = cs + ldf(self_b, tid, isb);
  }
  __syncthreads();

  // ---- projection: epb[b][p][e] = bf16x2(h0,h1) ----
  const int e = tid & 63;
  const int pp = tid >> 6;             // 4 p per pass
  float wv0[NC], wv1[NC];
#pragma unroll
  for (int c = 0; c < NC; c++) {
    wv0[c] = ewl[e*17 + c];            // h=0
    wv1[c] = ewl[(NE + e)*17 + c];     // h=1
  }
  unsigned* epb = (unsigned*)(ws + WS_EPB);
  const long base = (long)(b*NP + p0) * 64;
  for (int pass = 0; pass < 16; pass++) {
    const int p = pass*4 + pp;
    float a0 = 0.f, a1 = 0.f;
#pragma unroll
    for (int c = 0; c < NC; c++) {
      const float f = fl[c][p];        // broadcast
      a0 = fmaf(wv0[c], f, a0);
      a1 = fmaf(wv1[c], f, a1);
    }
    epb[base + (long)p*64 + e] = f2bf(a0) | (f2bf(a1) << 16);  // 256B/wave
  }

  if (tid < 64) {                      // pinfo {q0m,q1m,ss0,ss1}
    float q0=0.f, q1=0.f, s0=0.f, s1=0.f;
#pragma unroll
    for (int c = 0; c < NC; c++) {
      const float f = fl[c][tid];
      q0 = fmaf(s_wq[c],     f, q0);
      q1 = fmaf(s_wq[16+c],  f, q1);
      s0 = fmaf(s_wsc[c],    f, s0);
      s1 = fmaf(s_wsc[16+c], f, s1);
    }
    const int p = p0 + tid;
    bool mv;
    if (mbyte) mv = ((const unsigned char*)mask)[b*NP + p] != 0;
    else       mv = ((const int*)mask)[b*NP + p] != 0;
    float4 pi;
    pi.x = mv ? q0 : QINV;
    pi.y = mv ? q1 : QINV;
    pi.z = s0 + s_cself[0];
    pi.w = s1 + s_cself[1];
    ((float4*)(ws + WS_PINFO))[b*NP + p] = pi;
  }
}

// ---------------- kernel 2: serial-k softmax + gather + outputs -------------
// grid: NB*(NP/32) = 1024 blocks; phase1 = wave0 lanes<32 (lane=p, no shfl),
// phase2 = 4 waves x 8 p (lane=e)
__global__ void __launch_bounds__(256) k_main(
    const void* feat, const int* nidx,
    const void* edge_g, const void* edge_v, const void* edge_bias,
    const void* edge_m, const void* edge_b2,
    const void* nb_w, const void* nb_b,
    char* ws, void* out)
{
  __shared__ int sh_isb;
  __shared__ float sh_se[128], sh_cbe[128], sh_cnb[2];
  __shared__ uint2 ent[32][17];        // compacted {coef half2, idx*256}
  __shared__ unsigned char cntcm[32];  // cnt | (central_mask<<7)
  __shared__ float att_t[NE][33];
  __shared__ float gr_t[NE][33];

  const int tid  = threadIdx.x;
  const int w    = tid >> 6;
  const int lane = tid & 63;

  if (w == 0) {                        // dtype detection
    const unsigned short* u = (const unsigned short*)feat;
    int cnt = 0;
#pragma unroll
    for (int i = 0; i < 8; i++) {
      int ex = (u[lane*8 + i] >> 7) & 0xFF;
      cnt += (ex >= 100 && ex <= 135) ? 1 : 0;
    }
#pragma unroll
    for (int o = 32; o >= 1; o >>= 1) cnt += __shfl_xor(cnt, o);
    if (lane == 0) sh_isb = (cnt >= 460) ? 1 : 0;
  }
  __syncthreads();
  const int isb = sh_isb;

  if (tid < 128) {                     // fold se/cbe/cnb
    const int he = tid, h = tid >> 6;
    float se = ldf(edge_g, he, isb) * rsqrtf(ldf(edge_v, he, isb) + EPSV);
    float cb = se * (ldf(edge_bias, he, isb) - ldf(edge_m, he, isb)) + ldf(edge_b2, he, isb);
    sh_se[he]  = se;
    sh_cbe[he] = cb;
    float t = ldf(nb_w, he, isb) * cb;
#pragma unroll
    for (int o = 32; o >= 1; o >>= 1) t += __shfl_xor(t, o);
    if ((tid & 63) == 0) sh_cnb[h] = t + ldf(nb_b, h, isb);
  }
  __syncthreads();

  const float4* pinfo = (const float4*)(ws + WS_PINFO);
  const int bid = blockIdx.x;
  const int b  = (bid & 7)*2 + ((bid >> 3) & 1);   // XCD swizzle (matches k_proj)
  const int pt = bid >> 4;                         // 0..63
  const int p0 = pt * 32;

  // ---- phase 1: wave0 lanes 0..31, lane = p, all-register softmax ----
  if (w == 0 && lane < 32) {
    const int p = p0 + lane;
    const float cnb0 = sh_cnb[0], cnb1 = sh_cnb[1];
    const float4 Pc = pinfo[b*NP + p];
    const bool cm = (Pc.x > QTHR);

    int idx[NK];
    {
      const int4* n4 = (const int4*)(nidx + ((long)b*NP + p)*NK);
#pragma unroll
      for (int q = 0; q < 4; q++) {
        const int4 v = n4[q];
        idx[q*4+0] = v.x; idx[q*4+1] = v.y; idx[q*4+2] = v.z; idx[q*4+3] = v.w;
      }
    }
    __half2 lgp[NK];
    unsigned vmask = 0;
    float mx0 = -INFINITY, mx1 = -INFINITY;
#pragma unroll
    for (int k = 0; k < NK; k++) {
      const float2 P = *(const float2*)&pinfo[b*NP + idx[k]];  // q0m,q1m
      const bool valid = (P.x > QTHR);
      float l0 = Pc.z + P.x - Pc.x + cnb0;
      l0 = (l0 >= 0.f) ? l0 : NSLOPE * l0;
      float l1 = Pc.w + P.y - Pc.w + cnb1;   // placeholder fixed below
      l1 = Pc.w + P.y - Pc.y + cnb1;
      l1 = (l1 >= 0.f) ? l1 : NSLOPE * l1;
      l0 = valid ? l0 : -INFINITY;
      l1 = valid ? l1 : -INFINITY;
      vmask |= (valid ? 1u : 0u) << k;
      lgp[k] = __floats2half2_rn(l0, l1);
      mx0 = fmaxf(mx0, l0);
      mx1 = fmaxf(mx1, l1);
    }
    float sm0 = 0.f, sm1 = 0.f;
#pragma unroll
    for (int k = 0; k < NK; k++) {
      const float2 l = __half22float2(lgp[k]);
      sm0 += __expf(l.x - mx0);              // -inf -> 0
      sm1 += __expf(l.y - mx1);
    }
    const float inv0 = 1.f / sm0, inv1 = 1.f / sm1;
    int pos = 0;
#pragma unroll
    for (int k = 0; k < NK; k++) {
      if ((vmask >> k) & 1) {
        const float2 l = __half22float2(lgp[k]);
        const float c0 = __expf(l.x - mx0) * inv0;
        const float c1 = __expf(l.y - mx1) * inv1;
        const __half2 h2 = __floats2half2_rn(c0, c1);
        uint2 e;
        e.x = *(const unsigned*)&h2;
        e.y = ((unsigned)idx[k]) << 8;       // byte offset of 256B row
        ent[lane][pos] = e;
        pos++;
      }
    }
    cntcm[lane] = (unsigned char)(pos | (cm ? 0x80 : 0));
  }
  __syncthreads();

  // ---- phase 2: lane = e; bf16x2 row gathers from L2 ----
  const float se0 = sh_se[lane],  se1 = sh_se[NE + lane];
  const float cb0 = sh_cbe[lane], cb1 = sh_cbe[NE + lane];
  const char* epb_b = ws + WS_EPB + (long)b * NP * 256;

  for (int j = 0; j < 8; j++) {
    const int pl = w*8 + j;
    const unsigned cc = cntcm[pl];
    if (!(cc & 0x80)) { att_t[lane][pl] = 0.f; gr_t[lane][pl] = 0.f; continue; }
    const int cnt = cc & 0x7F;

    const unsigned rawp = *(const unsigned*)(epb_b + (long)(p0 + pl)*256 + lane*4);
    const float ra0 = bflo(rawp), ra1 = bfhi(rawp);
    const float cpe0 = cb0 - se0*ra0, cpe1 = cb1 - se1*ra1;

    float a0 = 0.f, a1 = 0.f;
    float mx0 = -INFINITY, mn0 = INFINITY, mx1 = -INFINITY, mn1 = INFINITY;
#pragma unroll 4
    for (int k = 0; k < cnt; k++) {
      const uint2 en = ent[pl][k];                       // LDS broadcast
      const float2 cf = __half22float2(*(const __half2*)&en.x);
      const unsigned v = *(const unsigned*)(epb_b + en.y + lane*4);  // 256B/wave
      const float v0 = bflo(v), v1 = bfhi(v);
      a0 = fmaf(cf.x, v0, a0);
      a1 = fmaf(cf.y, v1, a1);
      mx0 = fmaxf(mx0, v0); mn0 = fminf(mn0, v0);
      mx1 = fmaxf(mx1, v1); mn1 = fminf(mn1, v1);
    }
    const bool av = (cnt > 0);
    const float csel = av ? 1.f : 0.f;
    const float att0 = fmaxf(fmaf(se0, a0, cpe0*csel), 0.f);
    const float att1 = fmaxf(fmaf(se1, a1, cpe1*csel), 0.f);
    const float g0 = av ? fmaf(se0, (se0 >= 0.f) ? mx0 : mn0, cpe0) : 0.f;
    const float g1 = av ? fmaf(se1, (se1 >= 0.f) ? mx1 : mn1, cpe1) : 0.f;
    att_t[lane][pl] = fmaxf(att0, att1);
    gr_t[lane][pl]  = fmaxf(g0, g1);
  }
  __syncthreads();

  const long obase = (long)b * NE * NP;
  const long go = (long)NB * NE * NP;
  for (int i = tid; i < NE*32; i += 256) {
    const int ee = i >> 5, pp = i & 31;
    const long oi = obase + (long)ee * NP + p0 + pp;
    const float av = att_t[ee][pp], gv = gr_t[ee][pp];
    if (isb) {
      ((__hip_bfloat16*)out)[oi] = __float2bfloat16(av);
      ((__hip_bfloat16*)out)[oi + go] = __float2bfloat16(gv);
    } else {
      ((float*)out)[oi] = av;
      ((float*)out)[oi + go] = gv;
    }
  }
}

extern "C" void kernel_launch(void* const* d_in, const int* in_sizes, int n_in,
                              void* d_out, int out_size, void* d_ws, size_t ws_size,
                              hipStream_t stream)
{
  const void* feat      = d_in[0];
  const void* nidx      = d_in[1];
  const void* mask      = d_in[2];
  const void* node_w    = d_in[3];
  const void* node_g    = d_in[4];
  const void* node_b    = d_in[5];
  const void* node_m    = d_in[6];
  const void* node_v    = d_in[7];
  const void* edge_w    = d_in[8];
  const void* edge_bias = d_in[9];
  const void* edge_g    = d_in[10];
  const void* edge_b2   = d_in[11];
  const void* edge_m    = d_in[12];
  const void* edge_v    = d_in[13];
  const void* self_w    = d_in[14];
  const void* self_b    = d_in[15];
  const void* nb_w      = d_in[16];
  const void* nb_b      = d_in[17];
  char* ws = (char*)d_ws;

  hipLaunchKernelGGL(k_proj, dim3(NB*(NP/64)), dim3(256), 0, stream,
                     feat, mask, edge_w, node_w,
                     edge_g, edge_v,
                     node_g, node_v, node_b, node_m,
                     self_w, self_b, nb_w, ws);
  hipLaunchKernelGGL(k_main, dim3(NB*(NP/32)), dim3(256), 0, stream,
                     feat, (const int*)nidx,
                     edge_g, edge_v, edge_bias, edge_m, edge_b2,
                     nb_w, nb_b, ws, d_out);
}

// Round 6
// 119.670 us; speedup vs baseline: 1.2159x; 1.0256x over previous
//
#include <hip/hip_runtime.h>
#include <hip/hip_bf16.h>
#include <hip/hip_fp16.h>
#include <math.h>

#define NB 16
#define NC 16
#define NP 2048
#define NK 16
#define NE 64
#define NH 2
#define EPSV 1e-5f
#define NSLOPE 0.2f
#define QINV -1e30f
#define QTHR -1e29f

// workspace byte offsets (ws poisoned 0xAA each iter; fully rewritten each call)
// ws[0]=isb flag, ws[1]=mask-byte flag
#define WS_SECB  12288                 // float2[128] {se,cbe} interleaved = 1 KiB
#define WS_CNB2  13312                 // float[2]
#define WS_PINFO 16384                 // float4[B*P] = 2 MiB
#define WS_EPB   2162688               // uint[B*P*64] bf16x2(h0,h1) = 8 MiB

__device__ __forceinline__ float ldf(const void* p, int i, int isb) {
  return isb ? __bfloat162float(((const __hip_bfloat16*)p)[i]) : ((const float*)p)[i];
}
__device__ __forceinline__ unsigned f2bf(float f) {          // RNE f32->bf16 bits
  unsigned u = __float_as_uint(f);
  return (u + 0x7FFFu + ((u >> 16) & 1u)) >> 16;
}
__device__ __forceinline__ float bflo(unsigned v) { return __uint_as_float(v << 16); }
__device__ __forceinline__ float bfhi(unsigned v) { return __uint_as_float(v & 0xFFFF0000u); }

// ---------------- kernel 1: projection (bf16x2-packed) + pinfo + params -----
// grid: NB*(NP/64) = 512 blocks; XCD swizzle matches k_main
__global__ void __launch_bounds__(256) k_proj(
    const void* feat, const void* mask,
    const void* edge_w, const void* node_w,
    const void* edge_g, const void* edge_v, const void* edge_bias,
    const void* edge_m, const void* edge_b2,
    const void* node_g, const void* node_v, const void* node_b, const void* node_m,
    const void* self_w, const void* self_b, const void* nb_w, const void* nb_b,
    char* ws)
{
  __shared__ int sh_isb, sh_mbyte;
  __shared__ float ewl[128*17];        // padded [he][c]
  __shared__ float nwl[128*17];
  __shared__ float fl[NC][64];
  __shared__ float w2[128], wn[128], ctr[128];
  __shared__ float s_wq[32], s_wsc[32], s_cself[2];

  const int tid = threadIdx.x;
  const int w = tid >> 6, lane = tid & 63;

  if (w == 0) {      // bf16 N(0,1): exponent field in [100,135] for ~all samples
    const unsigned short* u = (const unsigned short*)feat;
    int cnt = 0;
#pragma unroll
    for (int i = 0; i < 8; i++) {
      int ex = (u[lane*8 + i] >> 7) & 0xFF;
      cnt += (ex >= 100 && ex <= 135) ? 1 : 0;
    }
#pragma unroll
    for (int o = 32; o >= 1; o >>= 1) cnt += __shfl_xor(cnt, o);
    if (lane == 0) sh_isb = (cnt >= 460) ? 1 : 0;
  }
  if (w == 1) {      // int32 0/1 mask has all non-aligned bytes zero
    const unsigned char* mb = (const unsigned char*)mask;
    int c = 0;
#pragma unroll
    for (int i = 0; i < 16; i++) {
      int ix = lane*16 + i;
      c += ((ix & 3) && mb[ix]) ? 1 : 0;
    }
#pragma unroll
    for (int o = 32; o >= 1; o >>= 1) c += __shfl_xor(c, o);
    if (lane == 0) sh_mbyte = (c > 0) ? 1 : 0;
  }
  __syncthreads();
  const int isb = sh_isb, mbyte = sh_mbyte;

  const int bid = blockIdx.x;
  const int b  = (bid & 7)*2 + ((bid >> 3) & 1);   // XCD swizzle
  const int pt = bid >> 4;                         // 0..31
  const int p0 = pt * 64;

  for (int i = tid; i < 128*16; i += 256) {
    const int he = i >> 4, c = i & 15;
    ewl[he*17 + c] = ldf(edge_w, i, isb);
    nwl[he*17 + c] = ldf(node_w, i, isb);
  }
  for (int i = tid; i < NC*64; i += 256) {
    int c = i >> 6, p = i & 63;
    fl[c][p] = ldf(feat, (b*NC + c)*NP + p0 + p, isb);
  }
  if (tid < 128) {
    const int he = tid, h = tid >> 6;
    float se = ldf(edge_g, he, isb) * rsqrtf(ldf(edge_v, he, isb) + EPSV);
    float cb = se * (ldf(edge_bias, he, isb) - ldf(edge_m, he, isb)) + ldf(edge_b2, he, isb);
    float ns = ldf(node_g, he, isb) * rsqrtf(ldf(node_v, he, isb) + EPSV);
    w2[he]  = ldf(nb_w, he, isb) * se;
    wn[he]  = ldf(self_w, he, isb) * ns;
    ctr[he] = ldf(self_w, he, isb) * (ldf(node_b, he, isb) - ldf(node_m, he, isb) * ns);
    if (bid == 0) {                    // persist folded params for k_main
      ((float2*)(ws + WS_SECB))[he] = make_float2(se, cb);
      float t = ldf(nb_w, he, isb) * cb;
#pragma unroll
      for (int o = 32; o >= 1; o >>= 1) t += __shfl_xor(t, o);
      if ((tid & 63) == 0)
        ((float*)(ws + WS_CNB2))[h] = t + ldf(nb_b, h, isb);
    }
  }
  if (bid == 0 && tid == 0) {
    ((int*)ws)[0] = isb;
    ((int*)ws)[1] = mbyte;
  }
  __syncthreads();
  if (tid < 32) {
    const int h = tid >> 4, c = tid & 15;
    float sq = 0.f, sn = 0.f;
#pragma unroll 8
    for (int e = 0; e < NE; e++) {
      sq += w2[h*NE+e] * ewl[(h*NE+e)*17 + c];
      sn += wn[h*NE+e] * nwl[(h*NE+e)*17 + c];
    }
    s_wq[tid]  = sq;
    s_wsc[tid] = sn;
  }
  if (tid < 2) {
    float cs = 0.f;
#pragma unroll 8
    for (int e = 0; e < NE; e++) cs += ctr[tid*NE+e];
    s_cself[tid] = cs + ldf(self_b, tid, isb);
  }
  __syncthreads();

  // ---- projection: epb[b][p][e] = bf16x2(h0,h1) ----
  const int e = tid & 63;
  const int pp = tid >> 6;             // 4 p per pass
  float wv0[NC], wv1[NC];
#pragma unroll
  for (int c = 0; c < NC; c++) {
    wv0[c] = ewl[e*17 + c];            // h=0
    wv1[c] = ewl[(NE + e)*17 + c];     // h=1
  }
  unsigned* epb = (unsigned*)(ws + WS_EPB);
  const long base = (long)(b*NP + p0) * 64;
  for (int pass = 0; pass < 16; pass++) {
    const int p = pass*4 + pp;
    float a0 = 0.f, a1 = 0.f;
#pragma unroll
    for (int c = 0; c < NC; c++) {
      const float f = fl[c][p];        // broadcast
      a0 = fmaf(wv0[c], f, a0);
      a1 = fmaf(wv1[c], f, a1);
    }
    epb[base + (long)p*64 + e] = f2bf(a0) | (f2bf(a1) << 16);  // 256B/wave
  }

  if (tid < 64) {                      // pinfo {q0m,q1m,ss0,ss1}
    float q0=0.f, q1=0.f, s0=0.f, s1=0.f;
#pragma unroll
    for (int c = 0; c < NC; c++) {
      const float f = fl[c][tid];
      q0 = fmaf(s_wq[c],     f, q0);
      q1 = fmaf(s_wq[16+c],  f, q1);
      s0 = fmaf(s_wsc[c],    f, s0);
      s1 = fmaf(s_wsc[16+c], f, s1);
    }
    const int p = p0 + tid;
    bool mv;
    if (mbyte) mv = ((const unsigned char*)mask)[b*NP + p] != 0;
    else       mv = ((const int*)mask)[b*NP + p] != 0;
    float4 pi;
    pi.x = mv ? q0 : QINV;
    pi.y = mv ? q1 : QINV;
    pi.z = s0 + s_cself[0];
    pi.w = s1 + s_cself[1];
    ((float4*)(ws + WS_PINFO))[b*NP + p] = pi;
  }
}

// ---------------- kernel 2: softmax + gather + outputs ----------------------
// grid: NB*(NP/32) = 1024 blocks
// phase 1: all 4 waves, 8 lanes/p, 2 k/lane (chain depth ~2 gathers)
// phase 2: 4 waves x 8 p (lane = e)
__global__ void __launch_bounds__(256) k_main(const int* nidx, char* ws, void* out)
{
  __shared__ float sh_se[128], sh_cbe[128], sh_cnb[2];
  __shared__ uint2 ent[32][17];        // compacted {coef half2, idx<<8}
  __shared__ unsigned char cntcm[32];  // cnt | (central_mask<<7)
  __shared__ float att_t[NE][33];
  __shared__ float gr_t[NE][33];

  const int tid  = threadIdx.x;
  const int w    = tid >> 6;
  const int lane = tid & 63;

  const int isb = ((const int*)ws)[0];
  if (tid < 128) {
    const float2 sc = ((const float2*)(ws + WS_SECB))[tid];
    sh_se[tid]  = sc.x;
    sh_cbe[tid] = sc.y;
  }
  if (tid < 2) sh_cnb[tid] = ((const float*)(ws + WS_CNB2))[tid];
  __syncthreads();

  const float4* pinfo = (const float4*)(ws + WS_PINFO);
  const int bid = blockIdx.x;
  const int b  = (bid & 7)*2 + ((bid >> 3) & 1);   // XCD swizzle (matches k_proj)
  const int pt = bid >> 4;                         // 0..63
  const int p0 = pt * 32;
  const float cnb0 = sh_cnb[0], cnb1 = sh_cnb[1];

  // ---- phase 1: pl = w*8 + lane/8, k = 2*(lane&7) + {0,1} ----
  {
    const int pl = w*8 + (lane >> 3);
    const int p  = p0 + pl;
    const int kk = (lane & 7) * 2;
    const float4 Pc = pinfo[b*NP + p];             // 8-lane broadcast
    const bool cm = (Pc.x > QTHR);
    const int2 iv = *(const int2*)(nidx + ((long)b*NP + p)*NK + kk);
    const float2 Q0 = *(const float2*)&pinfo[b*NP + iv.x];
    const float2 Q1 = *(const float2*)&pinfo[b*NP + iv.y];
    const bool v0 = (Q0.x > QTHR), v1 = (Q1.x > QTHR);

    float l00 = Pc.z + Q0.x - Pc.x + cnb0;  l00 = (l00 >= 0.f) ? l00 : NSLOPE*l00;
    float l01 = Pc.w + Q0.y - Pc.y + cnb1;  l01 = (l01 >= 0.f) ? l01 : NSLOPE*l01;
    float l10 = Pc.z + Q1.x - Pc.x + cnb0;  l10 = (l10 >= 0.f) ? l10 : NSLOPE*l10;
    float l11 = Pc.w + Q1.y - Pc.y + cnb1;  l11 = (l11 >= 0.f) ? l11 : NSLOPE*l11;
    l00 = v0 ? l00 : -INFINITY;  l01 = v0 ? l01 : -INFINITY;
    l10 = v1 ? l10 : -INFINITY;  l11 = v1 ? l11 : -INFINITY;

    float mx0 = fmaxf(l00, l10), mx1 = fmaxf(l01, l11);
#pragma unroll
    for (int o = 1; o <= 4; o <<= 1) {
      mx0 = fmaxf(mx0, __shfl_xor(mx0, o));
      mx1 = fmaxf(mx1, __shfl_xor(mx1, o));
    }
    const float e00 = __expf(l00 - mx0), e10 = __expf(l10 - mx0);
    const float e01 = __expf(l01 - mx1), e11 = __expf(l11 - mx1);
    float s0 = e00 + e10, s1 = e01 + e11;
#pragma unroll
    for (int o = 1; o <= 4; o <<= 1) {
      s0 += __shfl_xor(s0, o);
      s1 += __shfl_xor(s1, o);
    }
    const float inv0 = 1.f / s0, inv1 = 1.f / s1;

    unsigned vmask = ((v0 ? 1u : 0u) << kk) | ((v1 ? 1u : 0u) << (kk + 1));
#pragma unroll
    for (int o = 1; o <= 4; o <<= 1) vmask |= __shfl_xor(vmask, o);

    const int pos0 = __popc(vmask & ((1u << kk) - 1));
    if (v0) {
      const __half2 h2 = __floats2half2_rn(e00 * inv0, e01 * inv1);
      uint2 en; en.x = *(const unsigned*)&h2; en.y = ((unsigned)iv.x) << 8;
      ent[pl][pos0] = en;
    }
    if (v1) {
      const __half2 h2 = __floats2half2_rn(e10 * inv0, e11 * inv1);
      uint2 en; en.x = *(const unsigned*)&h2; en.y = ((unsigned)iv.y) << 8;
      ent[pl][pos0 + (v0 ? 1 : 0)] = en;
    }
    if ((lane & 7) == 0)
      cntcm[pl] = (unsigned char)(__popc(vmask) | (cm ? 0x80 : 0));
  }
  __syncthreads();

  // ---- phase 2: lane = e; bf16x2 row gathers from L2 ----
  const float se0 = sh_se[lane],  se1 = sh_se[NE + lane];
  const float cb0 = sh_cbe[lane], cb1 = sh_cbe[NE + lane];
  const char* epb_b = ws + WS_EPB + (long)b * NP * 256;

  for (int j = 0; j < 8; j++) {
    const int pl = w*8 + j;
    const unsigned cc = cntcm[pl];
    if (!(cc & 0x80)) { att_t[lane][pl] = 0.f; gr_t[lane][pl] = 0.f; continue; }
    const int cnt = cc & 0x7F;

    const unsigned rawp = *(const unsigned*)(epb_b + (long)(p0 + pl)*256 + lane*4);
    const float ra0 = bflo(rawp), ra1 = bfhi(rawp);
    const float cpe0 = cb0 - se0*ra0, cpe1 = cb1 - se1*ra1;

    float a0 = 0.f, a1 = 0.f;
    float mx0 = -INFINITY, mn0 = INFINITY, mx1 = -INFINITY, mn1 = INFINITY;
#pragma unroll 4
    for (int k = 0; k < cnt; k++) {
      const uint2 en = ent[pl][k];                       // LDS broadcast
      const float2 cf = __half22float2(*(const __half2*)&en.x);
      const unsigned v = *(const unsigned*)(epb_b + en.y + lane*4);  // 256B/wave
      const float v0 = bflo(v), v1 = bfhi(v);
      a0 = fmaf(cf.x, v0, a0);
      a1 = fmaf(cf.y, v1, a1);
      mx0 = fmaxf(mx0, v0); mn0 = fminf(mn0, v0);
      mx1 = fmaxf(mx1, v1); mn1 = fminf(mn1, v1);
    }
    const bool av = (cnt > 0);
    const float csel = av ? 1.f : 0.f;
    const float att0 = fmaxf(fmaf(se0, a0, cpe0*csel), 0.f);
    const float att1 = fmaxf(fmaf(se1, a1, cpe1*csel), 0.f);
    const float g0 = av ? fmaf(se0, (se0 >= 0.f) ? mx0 : mn0, cpe0) : 0.f;
    const float g1 = av ? fmaf(se1, (se1 >= 0.f) ? mx1 : mn1, cpe1) : 0.f;
    att_t[lane][pl] = fmaxf(att0, att1);
    gr_t[lane][pl]  = fmaxf(g0, g1);
  }
  __syncthreads();

  // ---- epilogue: paired stores (2 p per thread) ----
  const long obase = (long)b * NE * NP;
  const long go = (long)NB * NE * NP;
  for (int i = tid; i < NE*16; i += 256) {
    const int ee = i >> 4, pp = (i & 15) * 2;
    const long oi = obase + (long)ee * NP + p0 + pp;
    const float a0 = att_t[ee][pp], a1 = att_t[ee][pp+1];
    const float g0 = gr_t[ee][pp],  g1 = gr_t[ee][pp+1];
    if (isb) {
      __hip_bfloat16* o = (__hip_bfloat16*)out;
      *(ushort2*)&o[oi]      = make_ushort2((unsigned short)f2bf(a0), (unsigned short)f2bf(a1));
      *(ushort2*)&o[oi + go] = make_ushort2((unsigned short)f2bf(g0), (unsigned short)f2bf(g1));
    } else {
      float* o = (float*)out;
      *(float2*)&o[oi]      = make_float2(a0, a1);
      *(float2*)&o[oi + go] = make_float2(g0, g1);
    }
  }
}

extern "C" void kernel_launch(void* const* d_in, const int* in_sizes, int n_in,
                              void* d_out, int out_size, void* d_ws, size_t ws_size,
                              hipStream_t stream)
{
  const void* feat      = d_in[0];
  const void* nidx      = d_in[1];
  const void* mask      = d_in[2];
  const void* node_w    = d_in[3];
  const void* node_g    = d_in[4];
  const void* node_b    = d_in[5];
  const void* node_m    = d_in[6];
  const void* node_v    = d_in[7];
  const void* edge_w    = d_in[8];
  const void* edge_bias = d_in[9];
  const void* edge_g    = d_in[10];
  const void* edge_b2   = d_in[11];
  const void* edge_m    = d_in[12];
  const void* edge_v    = d_in[13];
  const void* self_w    = d_in[14];
  const void* self_b    = d_in[15];
  const void* nb_w      = d_in[16];
  const void* nb_b      = d_in[17];
  char* ws = (char*)d_ws;

  hipLaunchKernelGGL(k_proj, dim3(NB*(NP/64)), dim3(256), 0, stream,
                     feat, mask, edge_w, node_w,
                     edge_g, edge_v, edge_bias, edge_m, edge_b2,
                     node_g, node_v, node_b, node_m,
                     self_w, self_b, nb_w, nb_b, ws);
  hipLaunchKernelGGL(k_main, dim3(NB*(NP/32)), dim3(256), 0, stream,
                     (const int*)nidx, ws, d_out);
}

// Round 7
// 117.708 us; speedup vs baseline: 1.2362x; 1.0167x over previous
//
#include <hip/hip_runtime.h>
#include <hip/hip_bf16.h>
#include <hip/hip_fp16.h>
#include <math.h>

#define NB 16
#define NC 16
#define NP 2048
#define NK 16
#define NE 64
#define NH 2
#define EPSV 1e-5f
#define NSLOPE 0.2f
#define QINV -1e30f
#define QTHR -1e29f

// workspace byte offsets (ws poisoned 0xAA each iter; fully rewritten each call)
// ws[0]=isb flag, ws[1]=mask-byte flag
#define WS_SECB  12288                 // float2[128] {se,cbe} = 1 KiB
#define WS_CNB2  13312                 // float[2]
#define WS_PQ    16384                 // float2[B*P] {q0m,q1m} = 256 KiB
#define WS_PS    278528                // float2[B*P] {ss0,ss1} = 256 KiB
#define WS_EPB   2162688               // uint[B*P*64] bf16x2(h0,h1) = 8 MiB

__device__ __forceinline__ float ldf(const void* p, int i, int isb) {
  return isb ? __bfloat162float(((const __hip_bfloat16*)p)[i]) : ((const float*)p)[i];
}
__device__ __forceinline__ unsigned f2bf(float f) {          // RNE f32->bf16 bits
  unsigned u = __float_as_uint(f);
  return (u + 0x7FFFu + ((u >> 16) & 1u)) >> 16;
}
__device__ __forceinline__ float bflo(unsigned v) { return __uint_as_float(v << 16); }
__device__ __forceinline__ float bfhi(unsigned v) { return __uint_as_float(v & 0xFFFF0000u); }

// ---------------- kernel 1: projection (bf16x2, valid-p only) + pinfo -------
// grid: NB*(NP/64) = 512 blocks; XCD swizzle matches k_main
__global__ void __launch_bounds__(256) k_proj(
    const void* feat, const void* mask,
    const void* edge_w, const void* node_w,
    const void* edge_g, const void* edge_v, const void* edge_bias,
    const void* edge_m, const void* edge_b2,
    const void* node_g, const void* node_v, const void* node_b, const void* node_m,
    const void* self_w, const void* self_b, const void* nb_w, const void* nb_b,
    char* ws)
{
  __shared__ int sh_isb, sh_mbyte;
  __shared__ float ewl[128*17];        // padded [he][c]
  __shared__ float nwl[128*17];
  __shared__ float fl[NC][64];
  __shared__ float w2[128], wn[128], ctr[128];
  __shared__ float s_wq[32], s_wsc[32], s_cself[2];
  __shared__ unsigned char mtile[64];

  const int tid = threadIdx.x;
  const int w = tid >> 6, lane = tid & 63;

  if (w == 0) {      // bf16 N(0,1): exponent field in [100,135] for ~all samples
    const unsigned short* u = (const unsigned short*)feat;
    int cnt = 0;
#pragma unroll
    for (int i = 0; i < 8; i++) {
      int ex = (u[lane*8 + i] >> 7) & 0xFF;
      cnt += (ex >= 100 && ex <= 135) ? 1 : 0;
    }
#pragma unroll
    for (int o = 32; o >= 1; o >>= 1) cnt += __shfl_xor(cnt, o);
    if (lane == 0) sh_isb = (cnt >= 460) ? 1 : 0;
  }
  if (w == 1) {      // int32 0/1 mask has all non-aligned bytes zero
    const unsigned char* mb = (const unsigned char*)mask;
    int c = 0;
#pragma unroll
    for (int i = 0; i < 16; i++) {
      int ix = lane*16 + i;
      c += ((ix & 3) && mb[ix]) ? 1 : 0;
    }
#pragma unroll
    for (int o = 32; o >= 1; o >>= 1) c += __shfl_xor(c, o);
    if (lane == 0) sh_mbyte = (c > 0) ? 1 : 0;
  }
  __syncthreads();
  const int isb = sh_isb, mbyte = sh_mbyte;

  const int bid = blockIdx.x;
  const int b  = (bid & 7)*2 + ((bid >> 3) & 1);   // XCD swizzle
  const int pt = bid >> 4;                         // 0..31
  const int p0 = pt * 64;

  for (int i = tid; i < 128*16; i += 256) {
    const int he = i >> 4, c = i & 15;
    ewl[he*17 + c] = ldf(edge_w, i, isb);
    nwl[he*17 + c] = ldf(node_w, i, isb);
  }
  for (int i = tid; i < NC*64; i += 256) {
    int c = i >> 6, p = i & 63;
    fl[c][p] = ldf(feat, (b*NC + c)*NP + p0 + p, isb);
  }
  if (tid < 64) {
    bool mv;
    if (mbyte) mv = ((const unsigned char*)mask)[b*NP + p0 + tid] != 0;
    else       mv = ((const int*)mask)[b*NP + p0 + tid] != 0;
    mtile[tid] = mv ? 1 : 0;
  }
  if (tid >= 64 && tid < 192) {
    const int he = tid - 64, h = he >> 6;
    float se = ldf(edge_g, he, isb) * rsqrtf(ldf(edge_v, he, isb) + EPSV);
    float cb = se * (ldf(edge_bias, he, isb) - ldf(edge_m, he, isb)) + ldf(edge_b2, he, isb);
    float ns = ldf(node_g, he, isb) * rsqrtf(ldf(node_v, he, isb) + EPSV);
    w2[he]  = ldf(nb_w, he, isb) * se;
    wn[he]  = ldf(self_w, he, isb) * ns;
    ctr[he] = ldf(self_w, he, isb) * (ldf(node_b, he, isb) - ldf(node_m, he, isb) * ns);
    if (bid == 0) {                    // persist folded params for k_main
      ((float2*)(ws + WS_SECB))[he] = make_float2(se, cb);
      float t = ldf(nb_w, he, isb) * cb;
#pragma unroll
      for (int o = 32; o >= 1; o >>= 1) t += __shfl_xor(t, o);
      if ((he & 63) == 0)
        ((float*)(ws + WS_CNB2))[h] = t + ldf(nb_b, h, isb);
    }
  }
  if (bid == 0 && tid == 0) {
    ((int*)ws)[0] = isb;
    ((int*)ws)[1] = mbyte;
  }
  __syncthreads();

  // ---- wq/wsc fold: 128 threads = (h, c, e-quarter), 16 iters + 2 shfl ----
  if (tid < 128) {
    const int h = tid >> 6, c = (tid >> 2) & 15, eq = tid & 3;
    float sq = 0.f, sn = 0.f;
#pragma unroll
    for (int i = 0; i < 16; i++) {
      const int e = eq*16 + i;
      sq += w2[h*NE+e] * ewl[(h*NE+e)*17 + c];
      sn += wn[h*NE+e] * nwl[(h*NE+e)*17 + c];
    }
    sq += __shfl_xor(sq, 1); sq += __shfl_xor(sq, 2);
    sn += __shfl_xor(sn, 1); sn += __shfl_xor(sn, 2);
    if (eq == 0) { s_wq[h*16 + c] = sq; s_wsc[h*16 + c] = sn; }
  }
  if (tid >= 128 && tid < 136) {       // cself: 8 threads
    const int h = (tid - 128) >> 2, eq = tid & 3;
    float cs = 0.f;
#pragma unroll
    for (int i = 0; i < 16; i++) cs += ctr[h*NE + eq*16 + i];
    cs += __shfl_xor(cs, 1); cs += __shfl_xor(cs, 2);
    if (eq == 0) s_cself[h] = cs + ldf(self_b, h, isb);
  }
  __syncthreads();

  // ---- projection: epb[b][p][e] = bf16x2(h0,h1), valid p only ----
  const int e = tid & 63;
  const int pp = tid >> 6;             // wave w handles p = pass*4 + w
  float wv0[NC], wv1[NC];
#pragma unroll
  for (int c = 0; c < NC; c++) {
    wv0[c] = ewl[e*17 + c];            // h=0
    wv1[c] = ewl[(NE + e)*17 + c];     // h=1
  }
  unsigned* epb = (unsigned*)(ws + WS_EPB);
  const long base = (long)(b*NP + p0) * 64;
  for (int pass = 0; pass < 16; pass++) {
    const int p = pass*4 + pp;
    if (!mtile[p]) continue;           // wave-uniform skip: row never read
    float a0 = 0.f, a1 = 0.f;
#pragma unroll
    for (int c = 0; c < NC; c++) {
      const float f = fl[c][p];        // broadcast
      a0 = fmaf(wv0[c], f, a0);
      a1 = fmaf(wv1[c], f, a1);
    }
    epb[base + (long)p*64 + e] = f2bf(a0) | (f2bf(a1) << 16);  // 256B/wave
  }

  if (tid < 64) {                      // pinfo: q-pair + ss-pair
    float q0=0.f, q1=0.f, s0=0.f, s1=0.f;
#pragma unroll
    for (int c = 0; c < NC; c++) {
      const float f = fl[c][tid];
      q0 = fmaf(s_wq[c],     f, q0);
      q1 = fmaf(s_wq[16+c],  f, q1);
      s0 = fmaf(s_wsc[c],    f, s0);
      s1 = fmaf(s_wsc[16+c], f, s1);
    }
    const int p = p0 + tid;
    const bool mv = mtile[tid] != 0;
    ((float2*)(ws + WS_PQ))[b*NP + p] = make_float2(mv ? q0 : QINV, mv ? q1 : QINV);
    ((float2*)(ws + WS_PS))[b*NP + p] = make_float2(s0 + s_cself[0], s1 + s_cself[1]);
  }
}

// ---------------- kernel 2: softmax + gather + outputs ----------------------
// grid: NB*(NP/32) = 1024 blocks
// phase 1: all 4 waves, 8 lanes/p, 2 k/lane; phase 2: 4 waves x 8 p (lane=e)
__global__ void __launch_bounds__(256) k_main(const int* nidx, char* ws, void* out)
{
  __shared__ float sh_se[128], sh_cbe[128], sh_cnb[2];
  __shared__ uint2 ent[32][17];        // compacted {coef half2, idx<<8}
  __shared__ unsigned char cntcm[32];  // cnt | (central_mask<<7)
  __shared__ float att_t[NE][33];
  __shared__ float gr_t[NE][33];

  const int tid  = threadIdx.x;
  const int w    = tid >> 6;
  const int lane = tid & 63;

  const int isb = ((const int*)ws)[0];
  if (tid < 128) {
    const float2 sc = ((const float2*)(ws + WS_SECB))[tid];
    sh_se[tid]  = sc.x;
    sh_cbe[tid] = sc.y;
  }
  if (tid < 2) sh_cnb[tid] = ((const float*)(ws + WS_CNB2))[tid];
  __syncthreads();

  const float2* Pq = (const float2*)(ws + WS_PQ);
  const float2* Ps = (const float2*)(ws + WS_PS);
  const int bid = blockIdx.x;
  const int b  = (bid & 7)*2 + ((bid >> 3) & 1);   // XCD swizzle (matches k_proj)
  const int pt = bid >> 4;                         // 0..63
  const int p0 = pt * 32;
  const float cnb0 = sh_cnb[0], cnb1 = sh_cnb[1];

  // ---- phase 1: pl = w*8 + lane/8, k = 2*(lane&7) + {0,1} ----
  {
    const int pl = w*8 + (lane >> 3);
    const int p  = p0 + pl;
    const int kk = (lane & 7) * 2;
    const float2 Pcq = Pq[b*NP + p];               // 8-lane broadcast
    const float2 Pcs = Ps[b*NP + p];
    const bool cm = (Pcq.x > QTHR);
    const int2 iv = *(const int2*)(nidx + ((long)b*NP + p)*NK + kk);
    const float2 Q0 = Pq[b*NP + iv.x];
    const float2 Q1 = Pq[b*NP + iv.y];
    const bool v0 = (Q0.x > QTHR), v1 = (Q1.x > QTHR);

    float l00 = Pcs.x + Q0.x - Pcq.x + cnb0;  l00 = (l00 >= 0.f) ? l00 : NSLOPE*l00;
    float l01 = Pcs.y + Q0.y - Pcq.y + cnb1;  l01 = (l01 >= 0.f) ? l01 : NSLOPE*l01;
    float l10 = Pcs.x + Q1.x - Pcq.x + cnb0;  l10 = (l10 >= 0.f) ? l10 : NSLOPE*l10;
    float l11 = Pcs.y + Q1.y - Pcq.y + cnb1;  l11 = (l11 >= 0.f) ? l11 : NSLOPE*l11;
    l00 = v0 ? l00 : -INFINITY;  l01 = v0 ? l01 : -INFINITY;
    l10 = v1 ? l10 : -INFINITY;  l11 = v1 ? l11 : -INFINITY;

    float mx0 = fmaxf(l00, l10), mx1 = fmaxf(l01, l11);
#pragma unroll
    for (int o = 1; o <= 4; o <<= 1) {
      mx0 = fmaxf(mx0, __shfl_xor(mx0, o));
      mx1 = fmaxf(mx1, __shfl_xor(mx1, o));
    }
    const float e00 = __expf(l00 - mx0), e10 = __expf(l10 - mx0);
    const float e01 = __expf(l01 - mx1), e11 = __expf(l11 - mx1);
    float s0 = e00 + e10, s1 = e01 + e11;
#pragma unroll
    for (int o = 1; o <= 4; o <<= 1) {
      s0 += __shfl_xor(s0, o);
      s1 += __shfl_xor(s1, o);
    }
    const float inv0 = 1.f / s0, inv1 = 1.f / s1;

    unsigned vmask = ((v0 ? 1u : 0u) << kk) | ((v1 ? 1u : 0u) << (kk + 1));
#pragma unroll
    for (int o = 1; o <= 4; o <<= 1) vmask |= __shfl_xor(vmask, o);

    const int pos0 = __popc(vmask & ((1u << kk) - 1));
    if (v0) {
      const __half2 h2 = __floats2half2_rn(e00 * inv0, e01 * inv1);
      uint2 en; en.x = *(const unsigned*)&h2; en.y = ((unsigned)iv.x) << 8;
      ent[pl][pos0] = en;
    }
    if (v1) {
      const __half2 h2 = __floats2half2_rn(e10 * inv0, e11 * inv1);
      uint2 en; en.x = *(const unsigned*)&h2; en.y = ((unsigned)iv.y) << 8;
      ent[pl][pos0 + (v0 ? 1 : 0)] = en;
    }
    if ((lane & 7) == 0)
      cntcm[pl] = (unsigned char)(__popc(vmask) | (cm ? 0x80 : 0));
  }
  __syncthreads();

  // ---- phase 2: lane = e; bf16x2 row gathers from L2 ----
  const float se0 = sh_se[lane],  se1 = sh_se[NE + lane];
  const float cb0 = sh_cbe[lane], cb1 = sh_cbe[NE + lane];
  const char* epb_b = ws + WS_EPB + (long)b * NP * 256;

  for (int j = 0; j < 8; j++) {
    const int pl = w*8 + j;
    const unsigned cc = cntcm[pl];
    if (!(cc & 0x80)) { att_t[lane][pl] = 0.f; gr_t[lane][pl] = 0.f; continue; }
    const int cnt = cc & 0x7F;

    const unsigned rawp = *(const unsigned*)(epb_b + (long)(p0 + pl)*256 + lane*4);
    const float ra0 = bflo(rawp), ra1 = bfhi(rawp);
    const float cpe0 = cb0 - se0*ra0, cpe1 = cb1 - se1*ra1;

    float a0 = 0.f, a1 = 0.f;
    float mx0 = -INFINITY, mn0 = INFINITY, mx1 = -INFINITY, mn1 = INFINITY;
#pragma unroll 4
    for (int k = 0; k < cnt; k++) {
      const uint2 en = ent[pl][k];                       // LDS broadcast
      const float2 cf = __half22float2(*(const __half2*)&en.x);
      const unsigned v = *(const unsigned*)(epb_b + en.y + lane*4);  // 256B/wave
      const float v0 = bflo(v), v1 = bfhi(v);
      a0 = fmaf(cf.x, v0, a0);
      a1 = fmaf(cf.y, v1, a1);
      mx0 = fmaxf(mx0, v0); mn0 = fminf(mn0, v0);
      mx1 = fmaxf(mx1, v1); mn1 = fminf(mn1, v1);
    }
    const bool av = (cnt > 0);
    const float csel = av ? 1.f : 0.f;
    const float att0 = fmaxf(fmaf(se0, a0, cpe0*csel), 0.f);
    const float att1 = fmaxf(fmaf(se1, a1, cpe1*csel), 0.f);
    const float g0 = av ? fmaf(se0, (se0 >= 0.f) ? mx0 : mn0, cpe0) : 0.f;
    const float g1 = av ? fmaf(se1, (se1 >= 0.f) ? mx1 : mn1, cpe1) : 0.f;
    att_t[lane][pl] = fmaxf(att0, att1);
    gr_t[lane][pl]  = fmaxf(g0, g1);
  }
  __syncthreads();

  // ---- epilogue: paired stores (2 p per thread) ----
  const long obase = (long)b * NE * NP;
  const long go = (long)NB * NE * NP;
  for (int i = tid; i < NE*16; i += 256) {
    const int ee = i >> 4, pp = (i & 15) * 2;
    const long oi = obase + (long)ee * NP + p0 + pp;
    const float a0 = att_t[ee][pp], a1 = att_t[ee][pp+1];
    const float g0 = gr_t[ee][pp],  g1 = gr_t[ee][pp+1];
    if (isb) {
      __hip_bfloat16* o = (__hip_bfloat16*)out;
      *(ushort2*)&o[oi]      = make_ushort2((unsigned short)f2bf(a0), (unsigned short)f2bf(a1));
      *(ushort2*)&o[oi + go] = make_ushort2((unsigned short)f2bf(g0), (unsigned short)f2bf(g1));
    } else {
      float* o = (float*)out;
      *(float2*)&o[oi]      = make_float2(a0, a1);
      *(float2*)&o[oi + go] = make_float2(g0, g1);
    }
  }
}

extern "C" void kernel_launch(void* const* d_in, const int* in_sizes, int n_in,
                              void* d_out, int out_size, void* d_ws, size_t ws_size,
                              hipStream_t stream)
{
  const void* feat      = d_in[0];
  const void* nidx      = d_in[1];
  const void* mask      = d_in[2];
  const void* node_w    = d_in[3];
  const void* node_g    = d_in[4];
  const void* node_b    = d_in[5];
  const void* node_m    = d_in[6];
  const void* node_v    = d_in[7];
  const void* edge_w    = d_in[8];
  const void* edge_bias = d_in[9];
  const void* edge_g    = d_in[10];
  const void* edge_b2   = d_in[11];
  const void* edge_m    = d_in[12];
  const void* edge_v    = d_in[13];
  const void* self_w    = d_in[14];
  const void* self_b    = d_in[15];
  const void* nb_w      = d_in[16];
  const void* nb_b      = d_in[17];
  char* ws = (char*)d_ws;

  hipLaunchKernelGGL(k_proj, dim3(NB*(NP/64)), dim3(256), 0, stream,
                     feat, mask, edge_w, node_w,
                     edge_g, edge_v, edge_bias, edge_m, edge_b2,
                     node_g, node_v, node_b, node_m,
                     self_w, self_b, nb_w, nb_b, ws);
  hipLaunchKernelGGL(k_main, dim3(NB*(NP/32)), dim3(256), 0, stream,
                     (const int*)nidx, ws, d_out);
}